// Round 2
// 655.435 us; speedup vs baseline: 1.0494x; 1.0494x over previous
//
#include <hip/hip_runtime.h>
#include <hip/hip_bf16.h>
#include <stdint.h>

typedef unsigned short u16;
typedef unsigned char u8;
typedef unsigned int u32;
typedef __attribute__((ext_vector_type(8))) short frag8;   // 8 bf16 (4 VGPRs)
typedef __attribute__((ext_vector_type(4))) float f4;      // 4 f32 acc

#define N8K 8192
#define SK 4         // split-K slices for big GEMM (halved: Ctmp traffic now dominant)
#define NKT 256      // k-tiles (32 wide) across N8K
#define NT2 128      // k-tile PAIRS (64 wide) across N8K

// Fragment-native ("tiled") layouts, matching mfma_f32_16x16x32_bf16 operand maps:
//   lane l <-> (row = l&15, k = (l>>4)*8 + j), unit = 8 consecutive k at fixed row.
//   A codes: 2-BIT packed per T-PAIR: one dword per lane per (Rt,T2) holds 16 codes:
//     byte b: bits[1:0]=c(Teven,j=b)  [3:2]=c(Teven,j=b+4)
//             bits[5:4]=c(Todd ,j=b)  [7:6]=c(Todd ,j=b+4)
//     so decode = (w>>{0,2,4,6}) & 0x03030303 -> 4x expand4, fragment-ordered.
//   B-tiled (B-operand, [coltile][ktile][lane][8]) : Pt (k dim = node index)

__device__ __forceinline__ u16 f2bf(float f) {
  union { float f; unsigned u; } v; v.f = f;
  return (u16)((v.u + 0x7FFFu + ((v.u >> 16) & 1u)) >> 16);   // RNE
}
__device__ __forceinline__ float lrelu(float v) { return v > 0.f ? v : 0.01f * v; }

// expand 4 A-codes (bytes in w, values 0/1/2) -> 2 dwords = 4 bf16 {0,1,2}
__device__ __forceinline__ void expand4(u32 w, u32& o0, u32& o1) {
  u32 hi = __builtin_amdgcn_perm(0u, 0x00403F00u, w);
  u32 lo = __builtin_amdgcn_perm(0u, 0x00008000u, w);
  o0 = __builtin_amdgcn_perm(hi, lo, 0x05010400u);      // [lo0,hi0,lo1,hi1]
  o1 = __builtin_amdgcn_perm(hi, lo, 0x07030602u);      // [lo2,hi2,lo3,hi3]
}

// bit position of code (col in 0..63 within a T-pair) inside w[(col&31)>>3]
#define WQ(col) (((col) & 31) >> 3)
#define SHIFT(col) (8 * (((col) & 7) & 3) + 2 * (((col) & 7) >> 2) + 4 * ((col) >> 5))

// ---------------- deg: e -> A_hat 2-bit codes (T-pair packed) + dinv ----------------
__global__ __launch_bounds__(256) void k_deg(const int* __restrict__ e,
                                             u8* __restrict__ at,
                                             float* __restrict__ dinv) {
  int Rt = blockIdx.x;                     // 512 row-tiles
  int t = threadIdx.x;
  int rl = t & 15;
  int row = Rt * 16 + rl;
  int tg = t >> 4;
  int diagT2 = row >> 6;                   // T-pair containing the diagonal
  int cnt = 0;
  __shared__ int cs[256];
  for (int p = 0; p < 8; ++p) {
    int T2 = tg + 16 * p;                  // 0..127
    const int4* src = (const int4*)(e + (size_t)row * N8K + T2 * 64);
    u32 w[4] = {0u, 0u, 0u, 0u};
#pragma unroll
    for (int q8 = 0; q8 < 16; ++q8) {
      int4 v = src[q8];
      u32 c0 = (v.x != 0), c1 = (v.y != 0), c2 = (v.z != 0), c3 = (v.w != 0);
      cnt += (int)(c0 + c1 + c2 + c3);
      const int cb = q8 * 4;               // compile-time after unroll
      w[WQ(cb + 0)] |= c0 << SHIFT(cb + 0);
      w[WQ(cb + 1)] |= c1 << SHIFT(cb + 1);
      w[WQ(cb + 2)] |= c2 << SHIFT(cb + 2);
      w[WQ(cb + 3)] |= c3 << SHIFT(cb + 3);
    }
    if (T2 == diagT2) {                    // self-loop on diagonal: code += 1
      int col = row & 63;
      int qd = (col & 31) >> 3;
      u32 add = 1u << (8 * ((col & 7) & 3) + 2 * ((col & 7) >> 2) + 4 * (col >> 5));
#pragma unroll
      for (int q = 0; q < 4; ++q)
        if (q == qd) w[q] += add;          // field max becomes 2 (0b10), no carry
      cnt += 1;
    }
    u8* dst = at + ((size_t)(Rt * NT2 + T2) * 64 + rl) * 4;
#pragma unroll
    for (int q = 0; q < 4; ++q)
      *(u32*)(dst + (size_t)(16 * q) * 4) = w[q];
  }
  cs[t] = cnt;
  __syncthreads();
  if (t < 16) {
    int s = 0;
#pragma unroll
    for (int g = 0; g < 16; ++g) s += cs[t + 16 * g];
    dinv[Rt * 16 + t] = 1.0f / sqrtf((float)s);
  }
}

// ---------------- stage-1 small GEMM: Pt(B-tiled) = dinv * (x_f32 @ W1) ----------------
__global__ __launch_bounds__(256, 2) void k_sgemm1(const float* __restrict__ Xf,
                                                   const float* __restrict__ Wa,
                                                   const float* __restrict__ dinv,
                                                   u16* __restrict__ Pt) {
  const int KT = 4;
  __shared__ __attribute__((aligned(16))) u16 Wt[8 * 4 * 64 * 8];
  int t = threadIdx.x, mt = blockIdx.x;
  int lane = t & 63, wave = t >> 6;
  for (int u = t; u < 8 * KT * 64; u += 256) {
    int l = u & 63, T = (u >> 6) % KT, nt = (u >> 6) / KT;
    int n = nt * 16 + (l & 15);
    int k0 = T * 32 + (l >> 4) * 8;
    u16 tmp[8];
#pragma unroll
    for (int j = 0; j < 8; ++j) {
      int k = k0 + j;
      float v = (n < 64) ? Wa[k * 64 + n] : 0.f;
      tmp[j] = f2bf(v);
    }
    *(uint4*)&Wt[(size_t)u * 8] = *(const uint4*)tmp;
  }
  __syncthreads();
  int wm = (wave >> 1) * 64, wn = (wave & 1) * 64;
  int fm = lane & 15, q = lane >> 4;
  f4 acc[4][4];
#pragma unroll
  for (int m = 0; m < 4; ++m)
#pragma unroll
    for (int n = 0; n < 4; ++n) acc[m][n] = (f4){0.f, 0.f, 0.f, 0.f};
  for (int T = 0; T < KT; ++T) {
    frag8 a[4], b[4];
#pragma unroll
    for (int m = 0; m < 4; ++m) {
      int Rt = mt * 8 + (wm >> 4) + m;
      const float* px = Xf + (size_t)(Rt * 16 + fm) * 128 + T * 32 + q * 8;
      float4 v0 = *(const float4*)px, v1 = *(const float4*)(px + 4);
      u16 tmp[8] = {f2bf(v0.x), f2bf(v0.y), f2bf(v0.z), f2bf(v0.w),
                    f2bf(v1.x), f2bf(v1.y), f2bf(v1.z), f2bf(v1.w)};
      a[m] = *(const frag8*)tmp;
    }
#pragma unroll
    for (int n = 0; n < 4; ++n)
      b[n] = *(const frag8*)&Wt[((size_t)(((wn >> 4) + n) * KT + T) * 64 + lane) * 8];
#pragma unroll
    for (int m = 0; m < 4; ++m)
#pragma unroll
      for (int n = 0; n < 4; ++n)
        acc[m][n] = __builtin_amdgcn_mfma_f32_16x16x32_bf16(a[m], b[n], acc[m][n], 0, 0, 0);
  }
#pragma unroll
  for (int m = 0; m < 4; ++m) {
    int ibase = mt * 128 + wm + 16 * m + q * 4;
    float d0 = dinv[ibase], d1 = dinv[ibase + 1], d2 = dinv[ibase + 2], d3 = dinv[ibase + 3];
#pragma unroll
    for (int n = 0; n < 4; ++n) {
      u32 lo = (u32)f2bf(d0 * acc[m][n][0]) | ((u32)f2bf(d1 * acc[m][n][1]) << 16);
      u32 hi = (u32)f2bf(d2 * acc[m][n][2]) | ((u32)f2bf(d3 * acc[m][n][3]) << 16);
      u32 plo = __shfl_xor(lo, 16, 64);
      u32 phi = __shfl_xor(hi, 16, 64);
      if ((q & 1) == 0) {
        uint4 u; u.x = lo; u.y = hi; u.z = plo; u.w = phi;   // nodes gi..gi+7
        int gi = mt * 128 + wm + 16 * m + (q >> 1) * 8;
        int T2 = gi >> 5;
        int lB = fm + 16 * ((gi >> 3) & 3);
        int nt = (wn >> 4) + n;
        *(uint4*)(Pt + ((size_t)(nt * NKT + T2) * 64 + lB) * 8) = u;
      }
    }
  }
}

// ---------------- big GEMM (split-K): Ctmp[ks] = A_hat @ P ----------------
// Barrier-free, LDS-free; A codes are 2-bit T-pair-packed (1 dword -> 16 codes).
__global__ __launch_bounds__(256, 1) void k_bgemm(const u8* __restrict__ At,
                                                  const u16* __restrict__ Bt,
                                                  float* __restrict__ Ctmp) {
  int t = threadIdx.x;
  int mt = blockIdx.x, ks = blockIdx.y;
  int lane = t & 63, wave = t >> 6;
  int wm = (wave >> 1) * 64, wn = (wave & 1) * 64;
  f4 acc[4][4];
#pragma unroll
  for (int m = 0; m < 4; ++m)
#pragma unroll
    for (int n = 0; n < 4; ++n) acc[m][n] = (f4){0.f, 0.f, 0.f, 0.f};

  const int T20 = ks * 32;   // T-pair base; this slice covers T = ks*64 .. ks*64+63
  const u8*  Ab = At + ((size_t)((mt * 8 + (wm >> 4)) * NT2 + T20) * 64 + lane) * 4;
  const u16* Bb = Bt + ((size_t)(((wn >> 4)) * NKT + 2 * T20) * 64 + lane) * 8;

#pragma unroll 2
  for (int T2 = 0; T2 < 32; ++T2) {
    u32 w[4];
    frag8 aE[4], aO[4], bE[4], bO[4];
#pragma unroll
    for (int m = 0; m < 4; ++m)
      w[m] = *(const u32*)(Ab + (size_t)m * (NT2 * 256) + (size_t)T2 * 256);
#pragma unroll
    for (int n = 0; n < 4; ++n) {
      bE[n] = *(const frag8*)(Bb + (size_t)n * (NKT * 512) + (size_t)(2 * T2) * 512);
      bO[n] = *(const frag8*)(Bb + (size_t)n * (NKT * 512) + (size_t)(2 * T2) * 512 + 512);
    }
#pragma unroll
    for (int m = 0; m < 4; ++m) {
      u32 e0 = w[m] & 0x03030303u;
      u32 e1 = (w[m] >> 2) & 0x03030303u;
      u32 e2 = (w[m] >> 4) & 0x03030303u;
      u32 e3 = (w[m] >> 6) & 0x03030303u;
      uint4 rE, rO;
      expand4(e0, rE.x, rE.y); expand4(e1, rE.z, rE.w);   // T even, j0..7
      expand4(e2, rO.x, rO.y); expand4(e3, rO.z, rO.w);   // T odd,  j0..7
      aE[m] = *(const frag8*)&rE;
      aO[m] = *(const frag8*)&rO;
    }
#pragma unroll
    for (int m = 0; m < 4; ++m)
#pragma unroll
      for (int n = 0; n < 4; ++n)
        acc[m][n] = __builtin_amdgcn_mfma_f32_16x16x32_bf16(aE[m], bE[n], acc[m][n], 0, 0, 0);
#pragma unroll
    for (int m = 0; m < 4; ++m)
#pragma unroll
      for (int n = 0; n < 4; ++n)
        acc[m][n] = __builtin_amdgcn_mfma_f32_16x16x32_bf16(aO[m], bO[n], acc[m][n], 0, 0, 0);
  }

  float* Co = Ctmp + (size_t)ks * (N8K * 128);
  int fm = lane & 15, rbase = (lane >> 4) * 4;
#pragma unroll
  for (int m = 0; m < 4; ++m) {
    int i0 = mt * 128 + wm + 16 * m + rbase;
#pragma unroll
    for (int n = 0; n < 4; ++n) {
      int c = wn + 16 * n + fm;
#pragma unroll
      for (int r = 0; r < 4; ++r) Co[(size_t)(i0 + r) * 128 + c] = acc[m][n][r];
    }
  }
}

// ---------------- fused epilogue_k + sgemm_{k+1} (per 128-row block) ----------------
// mode 1: epi->h (64ch, bias bE), sgemm h@W2 (KT=2)
// mode 2: epi->z (128ch, bias bE, also z f32 out), sgemm z@[We|Wd1] (KT=4)
// mode 3: epi->re (bias bE, global tiled ret) + xd (bias bE2, LDS), sgemm xd@Wd2 (KT=2)
__global__ __launch_bounds__(256, 2) void k_fuse(const float* __restrict__ Ctmp,
                                                 const float* __restrict__ dinv,
                                                 const float* __restrict__ bE,
                                                 const float* __restrict__ bE2,
                                                 float* __restrict__ outZ,
                                                 u16* __restrict__ retG,
                                                 int mode,
                                                 const float* __restrict__ Wa, int wacols,
                                                 const float* __restrict__ Wb,
                                                 u16* __restrict__ Pt) {
  __shared__ __attribute__((aligned(16))) u16 Xs[8 * 4 * 64 * 8];   // 32 KB (KT<=4)
  __shared__ __attribute__((aligned(16))) u16 Wt[8 * 4 * 64 * 8];   // 32 KB
  int t = threadIdx.x, mt = blockIdx.x;
  int lane = t & 63, wave = t >> 6;
  const int KT = (mode == 2) ? 4 : 2;      // sgemm input k-tiles

  // ---- epilogue part ----
  int C8 = (mode == 1) ? 8 : 16;           // 8-ch units per row
  int totalU = 128 * C8;
  for (int u0 = t; u0 < totalU; u0 += 256) {
    int i = (mode == 1) ? (u0 >> 3) : (u0 >> 4);
    int c8 = (mode == 1) ? (u0 & 7) : (u0 & 15);
    int gi = mt * 128 + i;
    int c0 = c8 * 8;
    float v[8];
#pragma unroll
    for (int j = 0; j < 8; ++j) v[j] = 0.f;
#pragma unroll
    for (int k = 0; k < SK; ++k) {
      const float4* p = (const float4*)(Ctmp + (size_t)k * (N8K * 128) + (size_t)gi * 128 + c0);
      float4 x0 = p[0], x1 = p[1];
      v[0] += x0.x; v[1] += x0.y; v[2] += x0.z; v[3] += x0.w;
      v[4] += x1.x; v[5] += x1.y; v[6] += x1.z; v[7] += x1.w;
    }
    float di = dinv[gi];
    u16 ob[8];
    if (mode == 3 && c8 < 8) {             // re half -> global tiled (bias bE)
#pragma unroll
      for (int j = 0; j < 8; ++j) ob[j] = f2bf(lrelu(di * v[j] + bE[c0 + j]));
      int T = c8 >> 2, l = (i & 15) + 16 * (c8 & 3);
      *(uint4*)(retG + ((size_t)((gi >> 4) * 2 + T) * 64 + l) * 8) = *(const uint4*)ob;
    } else if (mode == 3) {                // xd half -> LDS tiled (bias bE2)
      int cl = c0 - 64;
#pragma unroll
      for (int j = 0; j < 8; ++j) ob[j] = f2bf(lrelu(di * v[j] + bE2[cl + j]));
      int cp = c8 - 8;
      int T = cp >> 2, l = (i & 15) + 16 * (cp & 3);
      *(uint4*)&Xs[(((i >> 4) * 2 + T) * 64 + l) * 8] = *(const uint4*)ob;
    } else {                               // mode 1/2 -> LDS tiled (bias bE)
#pragma unroll
      for (int j = 0; j < 8; ++j) v[j] = lrelu(di * v[j] + bE[c0 + j]);
#pragma unroll
      for (int j = 0; j < 8; ++j) ob[j] = f2bf(v[j]);
      int T = c8 >> 2, l = (i & 15) + 16 * (c8 & 3);
      *(uint4*)&Xs[(((i >> 4) * KT + T) * 64 + l) * 8] = *(const uint4*)ob;
      if (mode == 2) {                     // z also plain f32 output
        float4* po = (float4*)(outZ + (size_t)gi * 128 + c0);
        po[0] = (float4){v[0], v[1], v[2], v[3]};
        po[1] = (float4){v[4], v[5], v[6], v[7]};
      }
    }
  }

  // ---- stage W into LDS (B-tiled) ----
  for (int u = t; u < 8 * KT * 64; u += 256) {
    int l = u & 63, T = (u >> 6) % KT, nt = (u >> 6) / KT;
    int n = nt * 16 + (l & 15);
    int k0 = T * 32 + (l >> 4) * 8;
    u16 tmp[8];
#pragma unroll
    for (int j = 0; j < 8; ++j) {
      int k = k0 + j;
      float v = (n < wacols) ? Wa[k * wacols + n] : (Wb ? Wb[k * 64 + (n - 64)] : 0.f);
      tmp[j] = f2bf(v);
    }
    *(uint4*)&Wt[(size_t)u * 8] = *(const uint4*)tmp;
  }
  __syncthreads();

  // ---- sgemm part: Pt = dinv * (X @ W) ----
  int wm = (wave >> 1) * 64, wn = (wave & 1) * 64;
  int fm = lane & 15, q = lane >> 4;
  f4 acc[4][4];
#pragma unroll
  for (int m = 0; m < 4; ++m)
#pragma unroll
    for (int n = 0; n < 4; ++n) acc[m][n] = (f4){0.f, 0.f, 0.f, 0.f};
  for (int T = 0; T < KT; ++T) {
    frag8 a[4], b[4];
#pragma unroll
    for (int m = 0; m < 4; ++m)
      a[m] = *(const frag8*)&Xs[((size_t)(((wm >> 4) + m) * KT + T) * 64 + lane) * 8];
#pragma unroll
    for (int n = 0; n < 4; ++n)
      b[n] = *(const frag8*)&Wt[((size_t)(((wn >> 4) + n) * KT + T) * 64 + lane) * 8];
#pragma unroll
    for (int m = 0; m < 4; ++m)
#pragma unroll
      for (int n = 0; n < 4; ++n)
        acc[m][n] = __builtin_amdgcn_mfma_f32_16x16x32_bf16(a[m], b[n], acc[m][n], 0, 0, 0);
  }
#pragma unroll
  for (int m = 0; m < 4; ++m) {
    int ibase = mt * 128 + wm + 16 * m + q * 4;
    float d0 = dinv[ibase], d1 = dinv[ibase + 1], d2 = dinv[ibase + 2], d3 = dinv[ibase + 3];
#pragma unroll
    for (int n = 0; n < 4; ++n) {
      u32 lo = (u32)f2bf(d0 * acc[m][n][0]) | ((u32)f2bf(d1 * acc[m][n][1]) << 16);
      u32 hi = (u32)f2bf(d2 * acc[m][n][2]) | ((u32)f2bf(d3 * acc[m][n][3]) << 16);
      u32 plo = __shfl_xor(lo, 16, 64);
      u32 phi = __shfl_xor(hi, 16, 64);
      if ((q & 1) == 0) {
        uint4 u; u.x = lo; u.y = hi; u.z = plo; u.w = phi;
        int gi = mt * 128 + wm + 16 * m + (q >> 1) * 8;
        int T2 = gi >> 5;
        int lB = fm + 16 * ((gi >> 3) & 3);
        int nt = (wn >> 4) + n;
        *(uint4*)(Pt + ((size_t)(nt * NKT + T2) * 64 + lB) * 8) = u;
      }
    }
  }
}

// ---------------- final epilogue: x_out = lrelu(dinv*sum + bd2) ----------------
__global__ __launch_bounds__(256) void k_epi4(const float* __restrict__ Ctmp,
                                              const float* __restrict__ dinv,
                                              const float* __restrict__ bA,
                                              float* __restrict__ outF) {
  int idx = blockIdx.x * 256 + threadIdx.x;   // 131072 = 8192 * 16
  int i = idx >> 4, c8 = idx & 15;
  int c0 = c8 * 8;
  float v[8];
#pragma unroll
  for (int j = 0; j < 8; ++j) v[j] = 0.f;
#pragma unroll
  for (int k = 0; k < SK; ++k) {
    const float4* p = (const float4*)(Ctmp + (size_t)k * (N8K * 128) + (size_t)i * 128 + c0);
    float4 x0 = p[0], x1 = p[1];
    v[0] += x0.x; v[1] += x0.y; v[2] += x0.z; v[3] += x0.w;
    v[4] += x1.x; v[5] += x1.y; v[6] += x1.z; v[7] += x1.w;
  }
  float di = dinv[i];
#pragma unroll
  for (int j = 0; j < 8; ++j) v[j] = lrelu(di * v[j] + bA[c0 + j]);
  float4* po = (float4*)(outF + (size_t)i * 128 + c0);
  po[0] = (float4){v[0], v[1], v[2], v[3]};
  po[1] = (float4){v[4], v[5], v[6], v[7]};
}

// ---------------- recon = sigmoid(re @ re^T) ----------------
__global__ __launch_bounds__(256, 4) void k_recon(const u16* __restrict__ ret,
                                                  float* __restrict__ out) {
  int t = threadIdx.x;
  int bi = blockIdx.x, bj = blockIdx.y;
  int lane = t & 63, wave = t >> 6;
  int wm = (wave >> 1) * 64, wn = (wave & 1) * 64;
  int fm = lane & 15;
  f4 acc[4][4];
#pragma unroll
  for (int m = 0; m < 4; ++m)
#pragma unroll
    for (int n = 0; n < 4; ++n) acc[m][n] = (f4){0.f, 0.f, 0.f, 0.f};
#pragma unroll
  for (int T = 0; T < 2; ++T) {
    frag8 a[4], b[4];
#pragma unroll
    for (int m = 0; m < 4; ++m)
      a[m] = *(const frag8*)(ret + ((size_t)((bi * 8 + (wm >> 4) + m) * 2 + T) * 64 + lane) * 8);
#pragma unroll
    for (int n = 0; n < 4; ++n)
      b[n] = *(const frag8*)(ret + ((size_t)((bj * 8 + (wn >> 4) + n) * 2 + T) * 64 + lane) * 8);
#pragma unroll
    for (int m = 0; m < 4; ++m)
#pragma unroll
      for (int n = 0; n < 4; ++n)
        acc[m][n] = __builtin_amdgcn_mfma_f32_16x16x32_bf16(a[m], b[n], acc[m][n], 0, 0, 0);
  }
  int rbase = (lane >> 4) * 4;
#pragma unroll
  for (int m = 0; m < 4; ++m) {
#pragma unroll
    for (int n = 0; n < 4; ++n) {
      int gj = bj * 128 + wn + 16 * n + fm;
#pragma unroll
      for (int r = 0; r < 4; ++r) {
        int gi = bi * 128 + wm + 16 * m + rbase + r;
        float ex = __builtin_amdgcn_exp2f(acc[m][n][r] * -1.442695041f);
        out[(size_t)gi * N8K + gj] = __builtin_amdgcn_rcpf(1.0f + ex);
      }
    }
  }
}

extern "C" void kernel_launch(void* const* d_in, const int* in_sizes, int n_in,
                              void* d_out, int out_size, void* d_ws, size_t ws_size,
                              hipStream_t stream) {
  const float* x   = (const float*)d_in[0];
  const int*   e   = (const int*)d_in[1];
  const float* W1  = (const float*)d_in[2];
  const float* b1  = (const float*)d_in[3];
  const float* W2  = (const float*)d_in[4];
  const float* b2  = (const float*)d_in[5];
  const float* We  = (const float*)d_in[6];
  const float* be  = (const float*)d_in[7];
  const float* Wd1 = (const float*)d_in[8];
  const float* bd1 = (const float*)d_in[9];
  const float* Wd2 = (const float*)d_in[10];
  const float* bd2 = (const float*)d_in[11];

  float* out       = (float*)d_out;
  float* out_recon = out;                         // [8192*8192]
  float* out_x     = out + 67108864;              // [8192*128]
  float* out_z     = out + 67108864 + 1048576;    // [8192*128]

  // Scratch aliased into the recon region of d_out (overwritten only by k_recon last):
  u8*    at   = (u8*)d_out;                       // A_hat 2-bit codes: 16 MB
  float* Ctmp = out + 16777216;                   // split-K partials: SK*4 MB = 16 MB

  char* ws = (char*)d_ws;
  float* dinv = (float*)(ws);
  u16* Pt  = (u16*)(ws + 32768);                  // B-tiled, 2 MB
  u16* ret = (u16*)(ws + 32768 + 2097152);        // X-tiled re, 1 MB

  k_deg<<<512, 256, 0, stream>>>(e, at, dinv);

  // stage 1: P = dinv*(x@W1)
  k_sgemm1<<<64, 256, 0, stream>>>(x, W1, dinv, Pt);
  k_bgemm<<<dim3(64, SK), 256, 0, stream>>>(at, Pt, Ctmp);

  // epi1(h) + sgemm2(h@W2)
  k_fuse<<<64, 256, 0, stream>>>(Ctmp, dinv, b1, nullptr, nullptr, nullptr, 1,
                                 W2, 128, nullptr, Pt);
  k_bgemm<<<dim3(64, SK), 256, 0, stream>>>(at, Pt, Ctmp);

  // epi2(z; z f32 out) + sgemm3(z@[We|Wd1])
  k_fuse<<<64, 256, 0, stream>>>(Ctmp, dinv, b2, nullptr, out_z, nullptr, 2,
                                 We, 64, Wd1, Pt);
  k_bgemm<<<dim3(64, SK), 256, 0, stream>>>(at, Pt, Ctmp);

  // epi3(re -> global tiled, xd -> LDS) + sgemm4(xd@Wd2)
  k_fuse<<<64, 256, 0, stream>>>(Ctmp, dinv, be, bd1, nullptr, ret, 3,
                                 Wd2, 128, nullptr, Pt);
  k_bgemm<<<dim3(64, SK), 256, 0, stream>>>(at, Pt, Ctmp);

  // x_out
  k_epi4<<<512, 256, 0, stream>>>(Ctmp, dinv, bd2, out_x);

  // recon = sigmoid(re @ re^T) — overwrites the at/Ctmp scratch region last
  k_recon<<<dim3(64, 64), 256, 0, stream>>>(ret, out_recon);
}

// Round 3
// 645.038 us; speedup vs baseline: 1.0663x; 1.0161x over previous
//
#include <hip/hip_runtime.h>
#include <hip/hip_bf16.h>
#include <stdint.h>

typedef unsigned short u16;
typedef unsigned char u8;
typedef unsigned int u32;
typedef __attribute__((ext_vector_type(8))) short frag8;   // 8 bf16 (4 VGPRs)
typedef __attribute__((ext_vector_type(4))) float f4;      // 4 f32 acc

#define N8K 8192
#define SK 4         // split-K slices for big GEMM
#define NKT 256      // k-tiles (32 wide) across N8K
#define NT2 128      // k-tile PAIRS (64 wide) across N8K

// Fragment-native ("tiled") layouts, matching mfma_f32_16x16x32_bf16 operand maps:
//   lane l <-> (row = l&15, k = (l>>4)*8 + j), unit = 8 consecutive k at fixed row.
//   A codes: 2-BIT packed per T-PAIR: one dword per lane per (Rt,T2) holds 16 codes:
//     byte b: bits[1:0]=c(Teven,j=b)  [3:2]=c(Teven,j=b+4)
//             bits[5:4]=c(Todd ,j=b)  [7:6]=c(Todd ,j=b+4)
//     decode = (w>>{0,2,4,6}) & 0x03030303 -> 4x expand4, fragment-ordered.
//   B-tiled (B-operand, [coltile][ktile][lane][8]) : Pt (k dim = node index)

__device__ __forceinline__ u16 f2bf(float f) {
  union { float f; unsigned u; } v; v.f = f;
  return (u16)((v.u + 0x7FFFu + ((v.u >> 16) & 1u)) >> 16);   // RNE
}
__device__ __forceinline__ float lrelu(float v) { return v > 0.f ? v : 0.01f * v; }

// expand 4 A-codes (bytes in w, values 0/1/2) -> 2 dwords = 4 bf16 {0,1,2}
__device__ __forceinline__ void expand4(u32 w, u32& o0, u32& o1) {
  u32 hi = __builtin_amdgcn_perm(0u, 0x00403F00u, w);
  u32 lo = __builtin_amdgcn_perm(0u, 0x00008000u, w);
  o0 = __builtin_amdgcn_perm(hi, lo, 0x05010400u);      // [lo0,hi0,lo1,hi1]
  o1 = __builtin_amdgcn_perm(hi, lo, 0x07030602u);      // [lo2,hi2,lo3,hi3]
}

// bit position of code (col in 0..63 within a T-pair) inside w[(col&31)>>3]
#define WQ(col) (((col) & 31) >> 3)
#define SHIFT(col) (8 * (((col) & 7) & 3) + 2 * (((col) & 7) >> 2) + 4 * ((col) >> 5))

// ---------------- deg: e -> A_hat 2-bit codes (T-pair packed) + dinv ----------------
__global__ __launch_bounds__(256) void k_deg(const int* __restrict__ e,
                                             u8* __restrict__ at,
                                             float* __restrict__ dinv) {
  int Rt = blockIdx.x;                     // 512 row-tiles
  int t = threadIdx.x;
  int rl = t & 15;
  int row = Rt * 16 + rl;
  int tg = t >> 4;
  int diagT2 = row >> 6;                   // T-pair containing the diagonal
  int cnt = 0;
  __shared__ int cs[256];
  for (int p = 0; p < 8; ++p) {
    int T2 = tg + 16 * p;                  // 0..127
    const int4* src = (const int4*)(e + (size_t)row * N8K + T2 * 64);
    u32 w[4] = {0u, 0u, 0u, 0u};
#pragma unroll
    for (int q8 = 0; q8 < 16; ++q8) {
      int4 v = src[q8];
      u32 c0 = (v.x != 0), c1 = (v.y != 0), c2 = (v.z != 0), c3 = (v.w != 0);
      cnt += (int)(c0 + c1 + c2 + c3);
      const int cb = q8 * 4;               // compile-time after unroll
      w[WQ(cb + 0)] |= c0 << SHIFT(cb + 0);
      w[WQ(cb + 1)] |= c1 << SHIFT(cb + 1);
      w[WQ(cb + 2)] |= c2 << SHIFT(cb + 2);
      w[WQ(cb + 3)] |= c3 << SHIFT(cb + 3);
    }
    if (T2 == diagT2) {                    // self-loop on diagonal: code += 1
      int col = row & 63;
      int qd = (col & 31) >> 3;
      u32 add = 1u << (8 * ((col & 7) & 3) + 2 * ((col & 7) >> 2) + 4 * (col >> 5));
#pragma unroll
      for (int q = 0; q < 4; ++q)
        if (q == qd) w[q] += add;          // field max becomes 2 (0b10), no carry
      cnt += 1;
    }
    u8* dst = at + ((size_t)(Rt * NT2 + T2) * 64 + rl) * 4;
#pragma unroll
    for (int q = 0; q < 4; ++q)
      *(u32*)(dst + (size_t)(16 * q) * 4) = w[q];
  }
  cs[t] = cnt;
  __syncthreads();
  if (t < 16) {
    int s = 0;
#pragma unroll
    for (int g = 0; g < 16; ++g) s += cs[t + 16 * g];
    dinv[Rt * 16 + t] = 1.0f / sqrtf((float)s);
  }
}

// ---------------- stage-1 small GEMM: Pt(B-tiled, 4 coltiles) = dinv * (x_f32 @ W1) ----------------
// 64-row blocks, grid 128; waves row-split (no zero-padding: only 64 output cols).
__global__ __launch_bounds__(256, 2) void k_sgemm1(const float* __restrict__ Xf,
                                                   const float* __restrict__ Wa,
                                                   const float* __restrict__ dinv,
                                                   u16* __restrict__ Pt) {
  const int KT = 4;
  __shared__ __attribute__((aligned(16))) u16 Wt[4 * 4 * 64 * 8];   // 8 KB
  int t = threadIdx.x, mt = blockIdx.x;    // mt: 0..127
  int lane = t & 63, wave = t >> 6;
  for (int u = t; u < 4 * KT * 64; u += 256) {
    int l = u & 63, T = (u >> 6) % KT, nt = (u >> 6) / KT;
    int n = nt * 16 + (l & 15);            // n < 64 always
    int k0 = T * 32 + (l >> 4) * 8;
    u16 tmp[8];
#pragma unroll
    for (int j = 0; j < 8; ++j) tmp[j] = f2bf(Wa[(k0 + j) * 64 + n]);
    *(uint4*)&Wt[(size_t)u * 8] = *(const uint4*)tmp;
  }
  __syncthreads();
  int fm = lane & 15, q = lane >> 4;
  int Rt = mt * 4 + wave;                  // global row-tile
  f4 acc[4];
#pragma unroll
  for (int n = 0; n < 4; ++n) acc[n] = (f4){0.f, 0.f, 0.f, 0.f};
  for (int T = 0; T < KT; ++T) {
    const float* px = Xf + (size_t)(Rt * 16 + fm) * 128 + T * 32 + q * 8;
    float4 v0 = *(const float4*)px, v1 = *(const float4*)(px + 4);
    u16 tmp[8] = {f2bf(v0.x), f2bf(v0.y), f2bf(v0.z), f2bf(v0.w),
                  f2bf(v1.x), f2bf(v1.y), f2bf(v1.z), f2bf(v1.w)};
    frag8 a = *(const frag8*)tmp;
#pragma unroll
    for (int n = 0; n < 4; ++n) {
      frag8 b = *(const frag8*)&Wt[((size_t)(n * KT + T) * 64 + lane) * 8];
      acc[n] = __builtin_amdgcn_mfma_f32_16x16x32_bf16(a, b, acc[n], 0, 0, 0);
    }
  }
  int ibase = Rt * 16 + q * 4;
  float d0 = dinv[ibase], d1 = dinv[ibase + 1], d2 = dinv[ibase + 2], d3 = dinv[ibase + 3];
#pragma unroll
  for (int n = 0; n < 4; ++n) {
    u32 lo = (u32)f2bf(d0 * acc[n][0]) | ((u32)f2bf(d1 * acc[n][1]) << 16);
    u32 hi = (u32)f2bf(d2 * acc[n][2]) | ((u32)f2bf(d3 * acc[n][3]) << 16);
    u32 plo = __shfl_xor(lo, 16, 64);
    u32 phi = __shfl_xor(hi, 16, 64);
    if ((q & 1) == 0) {
      uint4 u; u.x = lo; u.y = hi; u.z = plo; u.w = phi;   // nodes gi..gi+7
      int gi = Rt * 16 + (q >> 1) * 8;
      int T2 = gi >> 5;
      int lB = fm + 16 * ((gi >> 3) & 3);
      *(uint4*)(Pt + ((size_t)(n * NKT + T2) * 64 + lB) * 8) = u;
    }
  }
}

// ---------------- big GEMM (split-K): Ctmp[ks] = A_hat @ P ----------------
// Barrier-free, LDS-free. NCT = output col-tiles (8 normal, 4 for stage 1).
// 64-row blocks, grid (128, SK) -> 2 blocks/CU (fixes 1-wave/SIMD latency cliff).
// NCT=8: waves 2x2 (32r x 64c each). NCT=4: waves row-split (16r x 64c, no decode redundancy).
template<int NCT>
__global__ __launch_bounds__(256, 2) void k_bgemm(const u8* __restrict__ At,
                                                  const u16* __restrict__ Bt,
                                                  float* __restrict__ Ctmp) {
  int t = threadIdx.x;
  int mt = blockIdx.x, ks = blockIdx.y;
  int lane = t & 63, wave = t >> 6;
  constexpr int WR = (NCT == 8) ? 2 : 1;   // row-tiles per wave
  const int rtb = (NCT == 8) ? (mt * 4 + (wave >> 1) * 2) : (mt * 4 + wave);
  const int ctb = (NCT == 8) ? ((wave & 1) * 4) : 0;
  f4 acc[WR][4];
#pragma unroll
  for (int m = 0; m < WR; ++m)
#pragma unroll
    for (int n = 0; n < 4; ++n) acc[m][n] = (f4){0.f, 0.f, 0.f, 0.f};

  const int T20 = ks * 32;   // T-pair base; slice covers T = ks*64 .. ks*64+63
  const u8*  Ab = At + ((size_t)(rtb * NT2 + T20) * 64 + lane) * 4;
  const u16* Bb = Bt + ((size_t)(ctb * NKT + 2 * T20) * 64 + lane) * 8;

#pragma unroll 2
  for (int T2 = 0; T2 < 32; ++T2) {
    u32 w[WR];
    frag8 aE[WR], aO[WR], bE[4], bO[4];
#pragma unroll
    for (int m = 0; m < WR; ++m)
      w[m] = *(const u32*)(Ab + (size_t)m * (NT2 * 256) + (size_t)T2 * 256);
#pragma unroll
    for (int n = 0; n < 4; ++n) {
      bE[n] = *(const frag8*)(Bb + (size_t)n * (NKT * 512) + (size_t)(2 * T2) * 512);
      bO[n] = *(const frag8*)(Bb + (size_t)n * (NKT * 512) + (size_t)(2 * T2) * 512 + 512);
    }
#pragma unroll
    for (int m = 0; m < WR; ++m) {
      u32 e0 = w[m] & 0x03030303u;
      u32 e1 = (w[m] >> 2) & 0x03030303u;
      u32 e2 = (w[m] >> 4) & 0x03030303u;
      u32 e3 = (w[m] >> 6) & 0x03030303u;
      uint4 rE, rO;
      expand4(e0, rE.x, rE.y); expand4(e1, rE.z, rE.w);   // T even, j0..7
      expand4(e2, rO.x, rO.y); expand4(e3, rO.z, rO.w);   // T odd,  j0..7
      aE[m] = *(const frag8*)&rE;
      aO[m] = *(const frag8*)&rO;
    }
#pragma unroll
    for (int m = 0; m < WR; ++m)
#pragma unroll
      for (int n = 0; n < 4; ++n)
        acc[m][n] = __builtin_amdgcn_mfma_f32_16x16x32_bf16(aE[m], bE[n], acc[m][n], 0, 0, 0);
#pragma unroll
    for (int m = 0; m < WR; ++m)
#pragma unroll
      for (int n = 0; n < 4; ++n)
        acc[m][n] = __builtin_amdgcn_mfma_f32_16x16x32_bf16(aO[m], bO[n], acc[m][n], 0, 0, 0);
  }

  constexpr int CST = NCT * 16;            // Ctmp row stride (cols)
  float* Co = Ctmp + (size_t)ks * (N8K * CST);
  int fm = lane & 15, rbase = (lane >> 4) * 4;
#pragma unroll
  for (int m = 0; m < WR; ++m) {
    int i0 = mt * 64 + ((NCT == 8) ? ((wave >> 1) * 32) : (wave * 16)) + 16 * m + rbase;
#pragma unroll
    for (int n = 0; n < 4; ++n) {
      int c = ctb * 16 + 16 * n + fm;
#pragma unroll
      for (int r = 0; r < 4; ++r) Co[(size_t)(i0 + r) * CST + c] = acc[m][n][r];
    }
  }
}

// ---------------- fused epilogue_k + sgemm_{k+1} (per 32-row block, grid 256) ----------------
// mode 1: epi->h (64ch, bias bE, Ctmp stride 64), sgemm h@W2 (KT=2)
// mode 2: epi->z (128ch, bias bE, also z f32 out), sgemm z@[We|Wd1] (KT=4)
// mode 3: epi->re (bias bE, global tiled ret) + xd (bias bE2, LDS), sgemm xd@Wd2 (KT=2)
__global__ __launch_bounds__(256, 2) void k_fuse(const float* __restrict__ Ctmp,
                                                 const float* __restrict__ dinv,
                                                 const float* __restrict__ bE,
                                                 const float* __restrict__ bE2,
                                                 float* __restrict__ outZ,
                                                 u16* __restrict__ retG,
                                                 int mode,
                                                 const float* __restrict__ Wa, int wacols,
                                                 const float* __restrict__ Wb,
                                                 u16* __restrict__ Pt) {
  __shared__ __attribute__((aligned(16))) u16 Xs[2 * 4 * 64 * 8];   // 8 KB (2 rowtiles x KT<=4)
  __shared__ __attribute__((aligned(16))) u16 Wt[8 * 4 * 64 * 8];   // 32 KB
  int t = threadIdx.x, mt = blockIdx.x;    // mt: 0..255 (32-row blocks)
  int lane = t & 63, wave = t >> 6;
  const int KT = (mode == 2) ? 4 : 2;      // sgemm input k-tiles
  const int cst = (mode == 1) ? 64 : 128;  // Ctmp row stride

  // ---- epilogue part ----
  int C8 = (mode == 1) ? 8 : 16;           // 8-ch units per row
  int totalU = 32 * C8;
  for (int u0 = t; u0 < totalU; u0 += 256) {
    int i = (mode == 1) ? (u0 >> 3) : (u0 >> 4);
    int c8 = (mode == 1) ? (u0 & 7) : (u0 & 15);
    int gi = mt * 32 + i;
    int c0 = c8 * 8;
    float v[8];
#pragma unroll
    for (int j = 0; j < 8; ++j) v[j] = 0.f;
#pragma unroll
    for (int k = 0; k < SK; ++k) {
      const float4* p = (const float4*)(Ctmp + (size_t)k * (N8K * cst) + (size_t)gi * cst + c0);
      float4 x0 = p[0], x1 = p[1];
      v[0] += x0.x; v[1] += x0.y; v[2] += x0.z; v[3] += x0.w;
      v[4] += x1.x; v[5] += x1.y; v[6] += x1.z; v[7] += x1.w;
    }
    float di = dinv[gi];
    u16 ob[8];
    if (mode == 3 && c8 < 8) {             // re half -> global tiled (bias bE)
#pragma unroll
      for (int j = 0; j < 8; ++j) ob[j] = f2bf(lrelu(di * v[j] + bE[c0 + j]));
      int T = c8 >> 2, l = (i & 15) + 16 * (c8 & 3);
      *(uint4*)(retG + ((size_t)((gi >> 4) * 2 + T) * 64 + l) * 8) = *(const uint4*)ob;
    } else if (mode == 3) {                // xd half -> LDS tiled (bias bE2)
      int cl = c0 - 64;
#pragma unroll
      for (int j = 0; j < 8; ++j) ob[j] = f2bf(lrelu(di * v[j] + bE2[cl + j]));
      int cp = c8 - 8;
      int T = cp >> 2, l = (i & 15) + 16 * (cp & 3);
      *(uint4*)&Xs[(((i >> 4) * KT + T) * 64 + l) * 8] = *(const uint4*)ob;
    } else {                               // mode 1/2 -> LDS tiled (bias bE)
#pragma unroll
      for (int j = 0; j < 8; ++j) v[j] = lrelu(di * v[j] + bE[c0 + j]);
#pragma unroll
      for (int j = 0; j < 8; ++j) ob[j] = f2bf(v[j]);
      int T = c8 >> 2, l = (i & 15) + 16 * (c8 & 3);
      *(uint4*)&Xs[(((i >> 4) * KT + T) * 64 + l) * 8] = *(const uint4*)ob;
      if (mode == 2) {                     // z also plain f32 output
        float4* po = (float4*)(outZ + (size_t)gi * 128 + c0);
        po[0] = (float4){v[0], v[1], v[2], v[3]};
        po[1] = (float4){v[4], v[5], v[6], v[7]};
      }
    }
  }

  // ---- stage W into LDS (B-tiled) ----
  for (int u = t; u < 8 * KT * 64; u += 256) {
    int l = u & 63, T = (u >> 6) % KT, nt = (u >> 6) / KT;
    int n = nt * 16 + (l & 15);
    int k0 = T * 32 + (l >> 4) * 8;
    u16 tmp[8];
#pragma unroll
    for (int j = 0; j < 8; ++j) {
      int k = k0 + j;
      float v = (n < wacols) ? Wa[k * wacols + n] : (Wb ? Wb[k * 64 + (n - 64)] : 0.f);
      tmp[j] = f2bf(v);
    }
    *(uint4*)&Wt[(size_t)u * 8] = *(const uint4*)tmp;
  }
  __syncthreads();

  // ---- sgemm part: Pt = dinv * (X @ W) ----
  int fm = lane & 15, q = lane >> 4;
  int rt = wave >> 1;                      // row-tile within block (0..1)
  int cb = (wave & 1) * 4;                 // col-tile base (0 or 4)
  f4 acc[4];
#pragma unroll
  for (int n = 0; n < 4; ++n) acc[n] = (f4){0.f, 0.f, 0.f, 0.f};
  for (int T = 0; T < KT; ++T) {
    frag8 a = *(const frag8*)&Xs[((size_t)(rt * KT + T) * 64 + lane) * 8];
#pragma unroll
    for (int n = 0; n < 4; ++n) {
      frag8 b = *(const frag8*)&Wt[((size_t)((cb + n) * KT + T) * 64 + lane) * 8];
      acc[n] = __builtin_amdgcn_mfma_f32_16x16x32_bf16(a, b, acc[n], 0, 0, 0);
    }
  }
  int ibase = mt * 32 + rt * 16 + q * 4;
  float d0 = dinv[ibase], d1 = dinv[ibase + 1], d2 = dinv[ibase + 2], d3 = dinv[ibase + 3];
#pragma unroll
  for (int n = 0; n < 4; ++n) {
    u32 lo = (u32)f2bf(d0 * acc[n][0]) | ((u32)f2bf(d1 * acc[n][1]) << 16);
    u32 hi = (u32)f2bf(d2 * acc[n][2]) | ((u32)f2bf(d3 * acc[n][3]) << 16);
    u32 plo = __shfl_xor(lo, 16, 64);
    u32 phi = __shfl_xor(hi, 16, 64);
    if ((q & 1) == 0) {
      uint4 u; u.x = lo; u.y = hi; u.z = plo; u.w = phi;
      int gi = mt * 32 + rt * 16 + (q >> 1) * 8;
      int T2 = gi >> 5;
      int lB = fm + 16 * ((gi >> 3) & 3);
      int nt = cb + n;
      *(uint4*)(Pt + ((size_t)(nt * NKT + T2) * 64 + lB) * 8) = u;
    }
  }
}

// ---------------- final epilogue: x_out = lrelu(dinv*sum + bd2) ----------------
__global__ __launch_bounds__(256) void k_epi4(const float* __restrict__ Ctmp,
                                              const float* __restrict__ dinv,
                                              const float* __restrict__ bA,
                                              float* __restrict__ outF) {
  int idx = blockIdx.x * 256 + threadIdx.x;   // 131072 = 8192 * 16
  int i = idx >> 4, c8 = idx & 15;
  int c0 = c8 * 8;
  float v[8];
#pragma unroll
  for (int j = 0; j < 8; ++j) v[j] = 0.f;
#pragma unroll
  for (int k = 0; k < SK; ++k) {
    const float4* p = (const float4*)(Ctmp + (size_t)k * (N8K * 128) + (size_t)i * 128 + c0);
    float4 x0 = p[0], x1 = p[1];
    v[0] += x0.x; v[1] += x0.y; v[2] += x0.z; v[3] += x0.w;
    v[4] += x1.x; v[5] += x1.y; v[6] += x1.z; v[7] += x1.w;
  }
  float di = dinv[i];
#pragma unroll
  for (int j = 0; j < 8; ++j) v[j] = lrelu(di * v[j] + bA[c0 + j]);
  float4* po = (float4*)(outF + (size_t)i * 128 + c0);
  po[0] = (float4){v[0], v[1], v[2], v[3]};
  po[1] = (float4){v[4], v[5], v[6], v[7]};
}

// ---------------- recon = sigmoid(re @ re^T) ----------------
__global__ __launch_bounds__(256, 4) void k_recon(const u16* __restrict__ ret,
                                                  float* __restrict__ out) {
  int t = threadIdx.x;
  int bi = blockIdx.x, bj = blockIdx.y;
  int lane = t & 63, wave = t >> 6;
  int wm = (wave >> 1) * 64, wn = (wave & 1) * 64;
  int fm = lane & 15;
  f4 acc[4][4];
#pragma unroll
  for (int m = 0; m < 4; ++m)
#pragma unroll
    for (int n = 0; n < 4; ++n) acc[m][n] = (f4){0.f, 0.f, 0.f, 0.f};
#pragma unroll
  for (int T = 0; T < 2; ++T) {
    frag8 a[4], b[4];
#pragma unroll
    for (int m = 0; m < 4; ++m)
      a[m] = *(const frag8*)(ret + ((size_t)((bi * 8 + (wm >> 4) + m) * 2 + T) * 64 + lane) * 8);
#pragma unroll
    for (int n = 0; n < 4; ++n)
      b[n] = *(const frag8*)(ret + ((size_t)((bj * 8 + (wn >> 4) + n) * 2 + T) * 64 + lane) * 8);
#pragma unroll
    for (int m = 0; m < 4; ++m)
#pragma unroll
      for (int n = 0; n < 4; ++n)
        acc[m][n] = __builtin_amdgcn_mfma_f32_16x16x32_bf16(a[m], b[n], acc[m][n], 0, 0, 0);
  }
  int rbase = (lane >> 4) * 4;
#pragma unroll
  for (int m = 0; m < 4; ++m) {
#pragma unroll
    for (int n = 0; n < 4; ++n) {
      int gj = bj * 128 + wn + 16 * n + fm;
#pragma unroll
      for (int r = 0; r < 4; ++r) {
        int gi = bi * 128 + wm + 16 * m + rbase + r;
        float ex = __builtin_amdgcn_exp2f(acc[m][n][r] * -1.442695041f);
        out[(size_t)gi * N8K + gj] = __builtin_amdgcn_rcpf(1.0f + ex);
      }
    }
  }
}

extern "C" void kernel_launch(void* const* d_in, const int* in_sizes, int n_in,
                              void* d_out, int out_size, void* d_ws, size_t ws_size,
                              hipStream_t stream) {
  const float* x   = (const float*)d_in[0];
  const int*   e   = (const int*)d_in[1];
  const float* W1  = (const float*)d_in[2];
  const float* b1  = (const float*)d_in[3];
  const float* W2  = (const float*)d_in[4];
  const float* b2  = (const float*)d_in[5];
  const float* We  = (const float*)d_in[6];
  const float* be  = (const float*)d_in[7];
  const float* Wd1 = (const float*)d_in[8];
  const float* bd1 = (const float*)d_in[9];
  const float* Wd2 = (const float*)d_in[10];
  const float* bd2 = (const float*)d_in[11];

  float* out       = (float*)d_out;
  float* out_recon = out;                         // [8192*8192]
  float* out_x     = out + 67108864;              // [8192*128]
  float* out_z     = out + 67108864 + 1048576;    // [8192*128]

  // Scratch aliased into the recon region of d_out (overwritten only by k_recon last):
  u8*    at   = (u8*)d_out;                       // A_hat 2-bit codes: 16 MB
  float* Ctmp = out + 16777216;                   // split-K partials: <= SK*4 MB = 16 MB

  char* ws = (char*)d_ws;
  float* dinv = (float*)(ws);
  u16* Pt  = (u16*)(ws + 32768);                  // B-tiled, 2 MB
  u16* ret = (u16*)(ws + 32768 + 2097152);        // X-tiled re, 1 MB

  k_deg<<<512, 256, 0, stream>>>(e, at, dinv);

  // stage 1: P = dinv*(x@W1) -- 64 cols only
  k_sgemm1<<<128, 256, 0, stream>>>(x, W1, dinv, Pt);
  k_bgemm<4><<<dim3(128, SK), 256, 0, stream>>>(at, Pt, Ctmp);

  // epi1(h) + sgemm2(h@W2)
  k_fuse<<<256, 256, 0, stream>>>(Ctmp, dinv, b1, nullptr, nullptr, nullptr, 1,
                                  W2, 128, nullptr, Pt);
  k_bgemm<8><<<dim3(128, SK), 256, 0, stream>>>(at, Pt, Ctmp);

  // epi2(z; z f32 out) + sgemm3(z@[We|Wd1])
  k_fuse<<<256, 256, 0, stream>>>(Ctmp, dinv, b2, nullptr, out_z, nullptr, 2,
                                  We, 64, Wd1, Pt);
  k_bgemm<8><<<dim3(128, SK), 256, 0, stream>>>(at, Pt, Ctmp);

  // epi3(re -> global tiled, xd -> LDS) + sgemm4(xd@Wd2)
  k_fuse<<<256, 256, 0, stream>>>(Ctmp, dinv, be, bd1, nullptr, ret, 3,
                                  Wd2, 128, nullptr, Pt);
  k_bgemm<8><<<dim3(128, SK), 256, 0, stream>>>(at, Pt, Ctmp);

  // x_out
  k_epi4<<<512, 256, 0, stream>>>(Ctmp, dinv, bd2, out_x);

  // recon = sigmoid(re @ re^T) -- overwrites the at/Ctmp scratch region last
  k_recon<<<dim3(64, 64), 256, 0, stream>>>(ret, out_recon);
}